// Round 15
// baseline (399.055 us; speedup 1.0000x reference)
//
#include <hip/hip_runtime.h>
#include <hip/hip_fp16.h>

// Problem constants
#define BB 4
#define TT 16
#define HH 512
#define WW 512
#define SP 528                        // padded row stride (halfs) of the f16 inter-pass buffer

// Tile: 256 threads = 4 waves; output 64x64; NO intra-block synchronization.
// Each wave privately stages its own 32-row x 80-px window (16 out rows + 16 halo)
// and computes rows 16wv..16wv+15 x 64 cols (4 col strips of 16 = 4 acc ILP).
#define BTILE 64
#define WVROWS 32                     // 16 out + 2*8 halo
#define WVROWB 160                    // 80 halfs per row
#define WVBUF (WVROWS * WVROWB)       // 5120 B = exactly 5 x 1024B DMA chunks
#define LDS_BYTES (4 * WVBUF)         // 20480 B -> 6+ blocks/CU

typedef _Float16 half8 __attribute__((ext_vector_type(8)));
typedef float f32x4 __attribute__((ext_vector_type(4)));

constexpr int kR[9] = {-8, -4, -2, -1, 0, 1, 2, 4, 8};   // merged tap rows

__device__ __forceinline__ int reflect_idx(int q, int n) {
    q = abs(q);
    if (q >= n) q = 2 * n - 2 - q;
    return q;
}

__device__ __forceinline__ void async_cp16(const __half* g, char* l) {
#if __has_builtin(__builtin_amdgcn_global_load_lds)
    __builtin_amdgcn_global_load_lds(
        (const __attribute__((address_space(1))) unsigned int*)g,
        (__attribute__((address_space(3))) unsigned int*)l, 16, 0, 0);
#else
    *reinterpret_cast<uint4*>(l) = *reinterpret_cast<const uint4*>(g);
#endif
}

// 27 B-fragment matrices (ch x tap-row), 32x16 f16 banded-Toeplitz in MFMA fragment order:
// frag[(ch*9+ri)*64 + lane][e], B[k][j], j=lane&15, k=8*(lane>>4)+e, val=merged_w[ch][r][k-8-j].
// Combined bias stored as float at halfs[27*64*8].
__global__ void pack_bfrag(const float* __restrict__ w1, const float* __restrict__ b1,
                           const float* __restrict__ w2, const float* __restrict__ b2,
                           const float* __restrict__ w3, const float* __restrict__ b3,
                           const float* __restrict__ sa, const float* __restrict__ sb,
                           const float* __restrict__ sc_, __half* __restrict__ bfrag) {
    const int tid = threadIdx.x;
    float s[3] = {sa[0], sb[0], sc_[0]};
    const float* wp[3] = {w1, w2, w3};
    for (int idx = tid; idx < 27 * 64; idx += blockDim.x) {
        int mat = idx >> 6;
        int lane = idx & 63;
        int ch = mat / 9, ri = mat % 9;
        int r = kR[ri];
        int j = lane & 15, kg = lane >> 4;
        union { __half h[8]; uint4 u; } v;
#pragma unroll
        for (int e = 0; e < 8; ++e) {
            int k = kg * 8 + e;
            int c = k - 8 - j;
            float a = 0.f;
            if (c >= -8 && c <= 8) {
                for (int b = 0; b < 3; ++b) {
                    int d = 1 << b;
                    if (r % d == 0 && c % d == 0) {
                        int rd = r / d, cd = c / d;
                        if (rd >= -2 && rd <= 2 && cd >= -2 && cd <= 2)
                            a += s[b] * wp[b][ch * 25 + (rd + 2) * 5 + (cd + 2)];
                    }
                }
            }
            v.h[e] = __float2half(a);
        }
        *reinterpret_cast<uint4*>(bfrag + idx * 8) = v.u;
    }
    if (tid == 0)
        *reinterpret_cast<float*>(bfrag + 27 * 64 * 8) = s[0] * b1[0] + s[1] * b2[0] + s[2] * b3[0];
}

// PASS 1: in = f32 x (unpadded), out = f16 ypad (stride SP, reflect-padded cols)
// PASS 2: in = f16 ypad,         out = f32 z   (unpadded)
template <int PASS>
__global__ __launch_bounds__(256, 6) void conv_mfma(const void* __restrict__ xin,
                                                    void* __restrict__ outp,
                                                    const __half* __restrict__ bfrag) {
    __shared__ char lds[LDS_BYTES];

    const int bt = blockIdx.z;
    const int t  = bt % TT;
    const int h0 = blockIdx.y * BTILE;
    const int w0 = blockIdx.x * BTILE;
    const int tid = threadIdx.x;
    const int lane = tid & 63;
    const int wv = tid >> 6;                  // wave id 0..3 = row strip

    char* buf = lds + wv * WVBUF;             // wave-PRIVATE window
    const int rowbase = h0 + 16 * wv - 8;     // global row of buf row 0

    const int tprev = (t == 0) ? 1 : t - 1;
    const int tnext = (t == TT - 1) ? TT - 2 : t + 1;
    const int bbase = (bt / TT) * TT;

    const void* fsrc[3];
    if constexpr (PASS == 1) {
        const float* x = (const float*)xin;
        const size_t fs = (size_t)HH * WW;
        fsrc[0] = x + (size_t)(bbase + tprev) * fs;
        fsrc[1] = x + (size_t)bt * fs;
        fsrc[2] = x + (size_t)(bbase + tnext) * fs;
    } else {
        const __half* y = (const __half*)xin;
        const size_t fsP = (size_t)HH * SP;
        fsrc[0] = y + (size_t)(bbase + tprev) * fsP;
        fsrc[1] = y + (size_t)bt * fsP;
        fsrc[2] = y + (size_t)(bbase + tnext) * fsP;
    }

    // ---- STAGE this wave's 32x80 window for channel ch (own-wave only, no sync) ----
    auto STAGE = [&](int ch) {
        if constexpr (PASS == 1) {
            const float* src = (const float*)fsrc[ch];
#pragma unroll
            for (int it = 0; it < 5; ++it) {           // 32 rows x 10 col8-groups = 5x64
                int k2 = it * 64 + lane;
                int row = k2 / 10;
                int c8  = k2 - row * 10;
                int gh = reflect_idx(rowbase + row, HH);
                int gb = w0 - 8 + c8 * 8;
                const float* rp = src + (size_t)gh * WW;
                union { __half h[8]; uint4 u; } cv;
                if (gb >= 0 && gb + 7 < WW) {
                    const float4 v0 = *reinterpret_cast<const float4*>(rp + gb);
                    const float4 v1 = *reinterpret_cast<const float4*>(rp + gb + 4);
                    cv.h[0] = __float2half(v0.x); cv.h[1] = __float2half(v0.y);
                    cv.h[2] = __float2half(v0.z); cv.h[3] = __float2half(v0.w);
                    cv.h[4] = __float2half(v1.x); cv.h[5] = __float2half(v1.y);
                    cv.h[6] = __float2half(v1.z); cv.h[7] = __float2half(v1.w);
                } else {
#pragma unroll
                    for (int e = 0; e < 8; ++e)
                        cv.h[e] = __float2half(rp[reflect_idx(gb + e, WW)]);
                }
                *reinterpret_cast<uint4*>(buf + row * WVROWB + c8 * 16) = cv.u;
            }
        } else {
            const __half* src = (const __half*)fsrc[ch];
#pragma unroll
            for (int c = 0; c < 5; ++c) {              // 5 x 1024B chunks, exact fit
                int byt = c * 1024 + lane * 16;
                int row  = byt / WVROWB;
                int colh = (byt - row * WVROWB) >> 1;
                int gh = reflect_idx(rowbase + row, HH);
                const __half* g = src + (size_t)gh * SP + (w0 + colh);  // pad+8 == halo-8
                async_cp16(g, buf + byt);
            }
        }
    };

    const float bias = *reinterpret_cast<const float*>(bfrag + 27 * 64 * 8);
    f32x4 acc0 = {bias, bias, bias, bias};
    f32x4 acc1 = acc0, acc2 = acc0, acc3 = acc0;

    const int i16 = lane & 15;
    const int kg  = lane >> 4;
    const char* aB = buf + i16 * WVROWB + kg * 16;   // buf row (i16 + r + 8) = literal imms

    // ---- COMPUTE channel ch from the private window ----
    auto COMPUTE = [&](int ch) {
        const __half* bp = bfrag + (size_t)ch * 9 * 512 + lane * 8;
        half8 bf[9];
#pragma unroll
        for (int ri = 0; ri < 9; ++ri)
            bf[ri] = *reinterpret_cast<const half8*>(bp + ri * 512);
#pragma unroll
        for (int ri = 0; ri < 9; ++ri) {
            const char* ar = aB + (kR[ri] + 8) * WVROWB;
            half8 a0 = *reinterpret_cast<const half8*>(ar);
            half8 a1 = *reinterpret_cast<const half8*>(ar + 32);
            half8 a2 = *reinterpret_cast<const half8*>(ar + 64);
            half8 a3 = *reinterpret_cast<const half8*>(ar + 96);
            __builtin_amdgcn_s_setprio(1);
            acc0 = __builtin_amdgcn_mfma_f32_16x16x32_f16(a0, bf[ri], acc0, 0, 0, 0);
            acc1 = __builtin_amdgcn_mfma_f32_16x16x32_f16(a1, bf[ri], acc1, 0, 0, 0);
            acc2 = __builtin_amdgcn_mfma_f32_16x16x32_f16(a2, bf[ri], acc2, 0, 0, 0);
            acc3 = __builtin_amdgcn_mfma_f32_16x16x32_f16(a3, bf[ri], acc3, 0, 0, 0);
            __builtin_amdgcn_s_setprio(0);
        }
    };

    // ---- Per-wave pipeline, ZERO barriers: stage -> wait-own -> compute ----
    STAGE(0);
#pragma unroll 1
    for (int ch = 0; ch < 3; ++ch) {
        if constexpr (PASS == 2)
            asm volatile("s_waitcnt vmcnt(0)" ::: "memory");   // own-wave DMA drained
        COMPUTE(ch);
        if (ch < 2) {
            if constexpr (PASS == 2)
                asm volatile("s_waitcnt lgkmcnt(0)" ::: "memory");  // reads done before DMA overwrites
            STAGE(ch + 1);
        }
    }

    // ---- Epilogue: tanh; C layout col=lane&15, row=(lane>>4)*4+reg ----
    if constexpr (PASS == 1) {
        __half* yp = (__half*)outp + (size_t)bt * HH * SP;
#pragma unroll
        for (int sc = 0; sc < 4; ++sc) {
            f32x4 a = (sc == 0) ? acc0 : (sc == 1) ? acc1 : (sc == 2) ? acc2 : acc3;
            const int wcol = w0 + sc * 16 + i16;
#pragma unroll
            for (int v2 = 0; v2 < 4; ++v2) {
                float z = a[v2];
                float e = __expf(2.0f * z);
                z = 1.0f - 2.0f / (e + 1.0f);
                __half hz = __float2half(z);
                __half* rb = yp + (size_t)(h0 + 16 * wv + kg * 4 + v2) * SP;
                rb[8 + wcol] = hz;
                if (wcol >= 1 && wcol <= 8)          rb[8 - wcol] = hz;       // left mirror
                else if (wcol >= 503 && wcol <= 510) rb[1030 - wcol] = hz;    // right mirror
            }
        }
    } else {
        float* dst = (float*)outp + (size_t)bt * HH * WW
                   + (size_t)(h0 + 16 * wv + kg * 4) * WW + (w0 + i16);
#pragma unroll
        for (int sc = 0; sc < 4; ++sc) {
            f32x4 a = (sc == 0) ? acc0 : (sc == 1) ? acc1 : (sc == 2) ? acc2 : acc3;
#pragma unroll
            for (int v2 = 0; v2 < 4; ++v2) {
                float z = a[v2];
                float e = __expf(2.0f * z);
                dst[(size_t)v2 * WW + sc * 16] = 1.0f - 2.0f / (e + 1.0f);
            }
        }
    }
}

extern "C" void kernel_launch(void* const* d_in, const int* in_sizes, int n_in,
                              void* d_out, int out_size, void* d_ws, size_t ws_size,
                              hipStream_t stream) {
    const float* x = (const float*)d_in[0];
    char* ws = (char*)d_ws;
    __half* bf1  = (__half*)ws;                        // 27.7 KB
    __half* bf2  = (__half*)(ws + 32768);              // 27.7 KB
    __half* ypad = (__half*)(ws + 65536);              // 64 x 512 x 528 f16 = 34.6 MB

    pack_bfrag<<<1, 256, 0, stream>>>((const float*)d_in[1], (const float*)d_in[2],
                                      (const float*)d_in[3], (const float*)d_in[4],
                                      (const float*)d_in[5], (const float*)d_in[6],
                                      (const float*)d_in[7], (const float*)d_in[8],
                                      (const float*)d_in[9], bf1);
    pack_bfrag<<<1, 256, 0, stream>>>((const float*)d_in[10], (const float*)d_in[11],
                                      (const float*)d_in[12], (const float*)d_in[13],
                                      (const float*)d_in[14], (const float*)d_in[15],
                                      (const float*)d_in[16], (const float*)d_in[17],
                                      (const float*)d_in[18], bf2);

    dim3 grid(WW / BTILE, HH / BTILE, BB * TT);   // 8 x 8 x 64
    conv_mfma<1><<<grid, 256, 0, stream>>>(x, ypad, bf1);
    conv_mfma<2><<<grid, 256, 0, stream>>>(ypad, d_out, bf2);
}

// Round 16
// 248.434 us; speedup vs baseline: 1.6063x; 1.6063x over previous
//
#include <hip/hip_runtime.h>
#include <hip/hip_fp16.h>

// Problem constants
#define BB 4
#define TT 16
#define HH 512
#define WW 512
#define SP 528                        // padded row stride (halfs) of the f16 inter-pass buffer

// 256 threads = 4 waves; output 64x64; ZERO intra-block barriers.
// Each wave privately stages its own 32-row x 80-px window (16 out + 16 halo rows)
// and computes rows 16wv..16wv+15 x 64 cols (4 col strips = 4 acc ILP).
#define BTILE 64
#define WVROWS 32
#define WVROWB 160                    // 80 halfs per row
#define WVBUF (WVROWS * WVROWB)       // 5120 B = exactly 5 x 1024B DMA chunks
#define LDS_BYTES (4 * WVBUF)         // 20480 B

typedef _Float16 half8 __attribute__((ext_vector_type(8)));
typedef float f32x4 __attribute__((ext_vector_type(4)));

constexpr int kR[9] = {-8, -4, -2, -1, 0, 1, 2, 4, 8};   // merged tap rows

__device__ __forceinline__ int reflect_idx(int q, int n) {
    q = abs(q);
    if (q >= n) q = 2 * n - 2 - q;
    return q;
}

__device__ __forceinline__ void async_cp16(const __half* g, char* l) {
#if __has_builtin(__builtin_amdgcn_global_load_lds)
    __builtin_amdgcn_global_load_lds(
        (const __attribute__((address_space(1))) unsigned int*)g,
        (__attribute__((address_space(3))) unsigned int*)l, 16, 0, 0);
#else
    *reinterpret_cast<uint4*>(l) = *reinterpret_cast<const uint4*>(g);
#endif
}

// 27 B-fragment matrices (ch x tap-row), 32x16 f16 banded-Toeplitz in MFMA fragment order:
// frag[(ch*9+ri)*64 + lane][e], B[k][j], j=lane&15, k=8*(lane>>4)+e, val=merged_w[ch][r][k-8-j].
// Combined bias stored as float at halfs[27*64*8].
__global__ void pack_bfrag(const float* __restrict__ w1, const float* __restrict__ b1,
                           const float* __restrict__ w2, const float* __restrict__ b2,
                           const float* __restrict__ w3, const float* __restrict__ b3,
                           const float* __restrict__ sa, const float* __restrict__ sb,
                           const float* __restrict__ sc_, __half* __restrict__ bfrag) {
    const int tid = threadIdx.x;
    float s[3] = {sa[0], sb[0], sc_[0]};
    const float* wp[3] = {w1, w2, w3};
    for (int idx = tid; idx < 27 * 64; idx += blockDim.x) {
        int mat = idx >> 6;
        int lane = idx & 63;
        int ch = mat / 9, ri = mat % 9;
        int r = kR[ri];
        int j = lane & 15, kg = lane >> 4;
        union { __half h[8]; uint4 u; } v;
#pragma unroll
        for (int e = 0; e < 8; ++e) {
            int k = kg * 8 + e;
            int c = k - 8 - j;
            float a = 0.f;
            if (c >= -8 && c <= 8) {
                for (int b = 0; b < 3; ++b) {
                    int d = 1 << b;
                    if (r % d == 0 && c % d == 0) {
                        int rd = r / d, cd = c / d;
                        if (rd >= -2 && rd <= 2 && cd >= -2 && cd <= 2)
                            a += s[b] * wp[b][ch * 25 + (rd + 2) * 5 + (cd + 2)];
                    }
                }
            }
            v.h[e] = __float2half(a);
        }
        *reinterpret_cast<uint4*>(bfrag + idx * 8) = v.u;
    }
    if (tid == 0)
        *reinterpret_cast<float*>(bfrag + 27 * 64 * 8) = s[0] * b1[0] + s[1] * b2[0] + s[2] * b3[0];
}

// ---- STAGE helpers: ALL control-flow static, src a named pointer ----
__device__ __forceinline__ void stage_f32(const float* __restrict__ src, char* buf,
                                          int rowbase, int w0, int lane) {
#pragma unroll
    for (int it = 0; it < 5; ++it) {               // 32 rows x 10 col8-groups = 5 x 64 lanes
        int k2 = it * 64 + lane;
        int row = k2 / 10;
        int c8  = k2 - row * 10;
        int gh = reflect_idx(rowbase + row, HH);
        int gb = w0 - 8 + c8 * 8;
        const float* rp = src + (size_t)gh * WW;
        union { __half h[8]; uint4 u; } cv;
        if (gb >= 0 && gb + 7 < WW) {
            const float4 v0 = *reinterpret_cast<const float4*>(rp + gb);
            const float4 v1 = *reinterpret_cast<const float4*>(rp + gb + 4);
            cv.h[0] = __float2half(v0.x); cv.h[1] = __float2half(v0.y);
            cv.h[2] = __float2half(v0.z); cv.h[3] = __float2half(v0.w);
            cv.h[4] = __float2half(v1.x); cv.h[5] = __float2half(v1.y);
            cv.h[6] = __float2half(v1.z); cv.h[7] = __float2half(v1.w);
        } else {
#pragma unroll
            for (int e = 0; e < 8; ++e)
                cv.h[e] = __float2half(rp[reflect_idx(gb + e, WW)]);
        }
        *reinterpret_cast<uint4*>(buf + row * WVROWB + c8 * 16) = cv.u;
    }
}

__device__ __forceinline__ void stage_f16(const __half* __restrict__ src, char* buf,
                                          int rowbase, int w0, int lane) {
#pragma unroll
    for (int c = 0; c < 5; ++c) {                  // 5 x 1024B DMA chunks, exact fit
        int byt = c * 1024 + lane * 16;
        int row  = byt / WVROWB;
        int colh = (byt - row * WVROWB) >> 1;
        int gh = reflect_idx(rowbase + row, HH);
        const __half* g = src + (size_t)gh * SP + (w0 + colh);   // pad +8 == halo -8
        async_cp16(g, buf + byt);
    }
}

// PASS 1: in = f32 x (unpadded), out = f16 ypad (stride SP, reflect-padded cols)
// PASS 2: in = f16 ypad,         out = f32 z   (unpadded)
template <int PASS>
__global__ __launch_bounds__(256, 5) void conv_mfma(const void* __restrict__ xin,
                                                    void* __restrict__ outp,
                                                    const __half* __restrict__ bfrag) {
    __shared__ char lds[LDS_BYTES];

    const int bt = blockIdx.z;
    const int t  = bt % TT;
    const int h0 = blockIdx.y * BTILE;
    const int w0 = blockIdx.x * BTILE;
    const int tid = threadIdx.x;
    const int lane = tid & 63;
    const int wv = tid >> 6;

    char* buf = lds + wv * WVBUF;                 // wave-PRIVATE window
    const int rowbase = h0 + 16 * wv - 8;

    const int tprev = (t == 0) ? 1 : t - 1;
    const int tnext = (t == TT - 1) ? TT - 2 : t + 1;
    const int bbase = (bt / TT) * TT;

    // Named frame pointers (NO arrays -> no scratch; r15 bug)
    const float *xf0 = nullptr, *xf1 = nullptr, *xf2 = nullptr;
    const __half *yf0 = nullptr, *yf1 = nullptr, *yf2 = nullptr;
    if constexpr (PASS == 1) {
        const float* x = (const float*)xin;
        const size_t fs = (size_t)HH * WW;
        xf0 = x + (size_t)(bbase + tprev) * fs;
        xf1 = x + (size_t)bt * fs;
        xf2 = x + (size_t)(bbase + tnext) * fs;
    } else {
        const __half* y = (const __half*)xin;
        const size_t fsP = (size_t)HH * SP;
        yf0 = y + (size_t)(bbase + tprev) * fsP;
        yf1 = y + (size_t)bt * fsP;
        yf2 = y + (size_t)(bbase + tnext) * fsP;
    }

    const float bias = *reinterpret_cast<const float*>(bfrag + 27 * 64 * 8);
    f32x4 acc0 = {bias, bias, bias, bias};
    f32x4 acc1 = acc0, acc2 = acc0, acc3 = acc0;

    const int i16 = lane & 15;
    const int kg  = lane >> 4;
    const char* aB = buf + i16 * WVROWB + kg * 16;

    // ---- fully static 3-channel sequence: stage -> wait(own) -> compute ----
#define STAGE_CH(CH)                                                             \
    do {                                                                         \
        if constexpr (PASS == 1)                                                 \
            stage_f32((CH) == 0 ? xf0 : (CH) == 1 ? xf1 : xf2, buf, rowbase, w0, lane); \
        else                                                                     \
            stage_f16((CH) == 0 ? yf0 : (CH) == 1 ? yf1 : yf2, buf, rowbase, w0, lane); \
    } while (0)

#define COMPUTE_CH(CH)                                                           \
    do {                                                                         \
        const __half* bp = bfrag + (size_t)(CH) * 9 * 512 + lane * 8;            \
        _Pragma("unroll")                                                        \
        for (int ri = 0; ri < 9; ++ri) {                                         \
            const half8 b = *reinterpret_cast<const half8*>(bp + ri * 512);      \
            const char* ar = aB + (kR[ri] + 8) * WVROWB;                         \
            half8 a0 = *reinterpret_cast<const half8*>(ar);                      \
            half8 a1 = *reinterpret_cast<const half8*>(ar + 32);                 \
            half8 a2 = *reinterpret_cast<const half8*>(ar + 64);                 \
            half8 a3 = *reinterpret_cast<const half8*>(ar + 96);                 \
            __builtin_amdgcn_s_setprio(1);                                       \
            acc0 = __builtin_amdgcn_mfma_f32_16x16x32_f16(a0, b, acc0, 0, 0, 0); \
            acc1 = __builtin_amdgcn_mfma_f32_16x16x32_f16(a1, b, acc1, 0, 0, 0); \
            acc2 = __builtin_amdgcn_mfma_f32_16x16x32_f16(a2, b, acc2, 0, 0, 0); \
            acc3 = __builtin_amdgcn_mfma_f32_16x16x32_f16(a3, b, acc3, 0, 0, 0); \
            __builtin_amdgcn_s_setprio(0);                                       \
        }                                                                        \
    } while (0)

    STAGE_CH(0);
    if constexpr (PASS == 2) asm volatile("s_waitcnt vmcnt(0)" ::: "memory");
    COMPUTE_CH(0);
    if constexpr (PASS == 2) asm volatile("s_waitcnt lgkmcnt(0)" ::: "memory");
    STAGE_CH(1);
    if constexpr (PASS == 2) asm volatile("s_waitcnt vmcnt(0)" ::: "memory");
    COMPUTE_CH(1);
    if constexpr (PASS == 2) asm volatile("s_waitcnt lgkmcnt(0)" ::: "memory");
    STAGE_CH(2);
    if constexpr (PASS == 2) asm volatile("s_waitcnt vmcnt(0)" ::: "memory");
    COMPUTE_CH(2);

#undef STAGE_CH
#undef COMPUTE_CH

    // ---- Epilogue: tanh; C layout col=lane&15, row=(lane>>4)*4+reg ----
    if constexpr (PASS == 1) {
        __half* yp = (__half*)outp + (size_t)bt * HH * SP;
#pragma unroll
        for (int sc = 0; sc < 4; ++sc) {
            f32x4 a = (sc == 0) ? acc0 : (sc == 1) ? acc1 : (sc == 2) ? acc2 : acc3;
            const int wcol = w0 + sc * 16 + i16;
#pragma unroll
            for (int v2 = 0; v2 < 4; ++v2) {
                float z = a[v2];
                float e = __expf(2.0f * z);
                z = 1.0f - 2.0f / (e + 1.0f);
                __half hz = __float2half(z);
                __half* rb = yp + (size_t)(h0 + 16 * wv + kg * 4 + v2) * SP;
                rb[8 + wcol] = hz;
                if (wcol >= 1 && wcol <= 8)          rb[8 - wcol] = hz;       // left mirror
                else if (wcol >= 503 && wcol <= 510) rb[1030 - wcol] = hz;    // right mirror
            }
        }
    } else {
        float* dst = (float*)outp + (size_t)bt * HH * WW
                   + (size_t)(h0 + 16 * wv + kg * 4) * WW + (w0 + i16);
#pragma unroll
        for (int sc = 0; sc < 4; ++sc) {
            f32x4 a = (sc == 0) ? acc0 : (sc == 1) ? acc1 : (sc == 2) ? acc2 : acc3;
#pragma unroll
            for (int v2 = 0; v2 < 4; ++v2) {
                float z = a[v2];
                float e = __expf(2.0f * z);
                dst[(size_t)v2 * WW + sc * 16] = 1.0f - 2.0f / (e + 1.0f);
            }
        }
    }
}

extern "C" void kernel_launch(void* const* d_in, const int* in_sizes, int n_in,
                              void* d_out, int out_size, void* d_ws, size_t ws_size,
                              hipStream_t stream) {
    const float* x = (const float*)d_in[0];
    char* ws = (char*)d_ws;
    __half* bf1  = (__half*)ws;                        // 27.7 KB
    __half* bf2  = (__half*)(ws + 32768);              // 27.7 KB
    __half* ypad = (__half*)(ws + 65536);              // 64 x 512 x 528 f16 = 34.6 MB

    pack_bfrag<<<1, 256, 0, stream>>>((const float*)d_in[1], (const float*)d_in[2],
                                      (const float*)d_in[3], (const float*)d_in[4],
                                      (const float*)d_in[5], (const float*)d_in[6],
                                      (const float*)d_in[7], (const float*)d_in[8],
                                      (const float*)d_in[9], bf1);
    pack_bfrag<<<1, 256, 0, stream>>>((const float*)d_in[10], (const float*)d_in[11],
                                      (const float*)d_in[12], (const float*)d_in[13],
                                      (const float*)d_in[14], (const float*)d_in[15],
                                      (const float*)d_in[16], (const float*)d_in[17],
                                      (const float*)d_in[18], bf2);

    dim3 grid(WW / BTILE, HH / BTILE, BB * TT);   // 8 x 8 x 64
    conv_mfma<1><<<grid, 256, 0, stream>>>(x, ypad, bf1);
    conv_mfma<2><<<grid, 256, 0, stream>>>(ypad, d_out, bf2);
}

// Round 17
// 157.794 us; speedup vs baseline: 2.5290x; 1.5744x over previous
//
#include <hip/hip_runtime.h>
#include <hip/hip_fp16.h>

// Problem constants
#define BB 4
#define TT 16
#define HH 512
#define WW 512
#define SP 528                        // padded row stride (halfs) of the f16 inter-pass buffer

// 256 threads = 4 waves; output 64x64. Wave wv owns rows 16wv..16wv+15 x 64 cols.
// LDS: 2 ping-pong channel planes + resident copy of all 27 B-fragments.
#define BTILE 64
#define ROWB 160                      // plane row stride bytes (80 halfs)
#define PROWS 80                      // 64 + 2*8 halo
#define PLANE_BYTES (PROWS * ROWB)    // 12800
#define BLDS_OFF (2 * PLANE_BYTES)    // 25600
#define BFRAG_BYTES 27648             // 27 mats x 64 lanes x 16 B
#define LDS_BYTES (BLDS_OFF + BFRAG_BYTES)   // 53248 -> 3 blocks/CU

typedef _Float16 half8 __attribute__((ext_vector_type(8)));
typedef float f32x4 __attribute__((ext_vector_type(4)));

constexpr int kR[9] = {-8, -4, -2, -1, 0, 1, 2, 4, 8};   // merged tap rows

__device__ __forceinline__ int reflect_idx(int q, int n) {
    q = abs(q);
    if (q >= n) q = 2 * n - 2 - q;
    return q;
}

__device__ __forceinline__ void async_cp16(const void* g, char* l) {
#if __has_builtin(__builtin_amdgcn_global_load_lds)
    __builtin_amdgcn_global_load_lds(
        (const __attribute__((address_space(1))) unsigned int*)g,
        (__attribute__((address_space(3))) unsigned int*)l, 16, 0, 0);
#else
    *reinterpret_cast<uint4*>(l) = *reinterpret_cast<const uint4*>(g);
#endif
}

// 27 B-fragment matrices (ch x tap-row), 32x16 f16 banded-Toeplitz in MFMA fragment order:
// frag[(ch*9+ri)*64 + lane][e], B[k][j], j=lane&15, k=8*(lane>>4)+e, val=merged_w[ch][r][k-8-j].
// Combined bias stored as float at halfs[27*64*8].
__global__ void pack_bfrag(const float* __restrict__ w1, const float* __restrict__ b1,
                           const float* __restrict__ w2, const float* __restrict__ b2,
                           const float* __restrict__ w3, const float* __restrict__ b3,
                           const float* __restrict__ sa, const float* __restrict__ sb,
                           const float* __restrict__ sc_, __half* __restrict__ bfrag) {
    const int tid = threadIdx.x;
    float s[3] = {sa[0], sb[0], sc_[0]};
    const float* wp[3] = {w1, w2, w3};
    for (int idx = tid; idx < 27 * 64; idx += blockDim.x) {
        int mat = idx >> 6;
        int lane = idx & 63;
        int ch = mat / 9, ri = mat % 9;
        int r = kR[ri];
        int j = lane & 15, kg = lane >> 4;
        union { __half h[8]; uint4 u; } v;
#pragma unroll
        for (int e = 0; e < 8; ++e) {
            int k = kg * 8 + e;
            int c = k - 8 - j;
            float a = 0.f;
            if (c >= -8 && c <= 8) {
                for (int b = 0; b < 3; ++b) {
                    int d = 1 << b;
                    if (r % d == 0 && c % d == 0) {
                        int rd = r / d, cd = c / d;
                        if (rd >= -2 && rd <= 2 && cd >= -2 && cd <= 2)
                            a += s[b] * wp[b][ch * 25 + (rd + 2) * 5 + (cd + 2)];
                    }
                }
            }
            v.h[e] = __float2half(a);
        }
        *reinterpret_cast<uint4*>(bfrag + idx * 8) = v.u;
    }
    if (tid == 0)
        *reinterpret_cast<float*>(bfrag + 27 * 64 * 8) = s[0] * b1[0] + s[1] * b2[0] + s[2] * b3[0];
}

// ---- STAGE helpers: static control flow, named src pointers ----
__device__ __forceinline__ void stage_f32(const float* __restrict__ src, char* buf,
                                          int h0, int w0, int tid) {
    for (int k2 = tid; k2 < PROWS * 10; k2 += 256) {
        int row = k2 / 10;
        int c8  = k2 - row * 10;
        int gh = reflect_idx(h0 - 8 + row, HH);
        int gb = w0 - 8 + c8 * 8;
        const float* rp = src + (size_t)gh * WW;
        union { __half2 h2[4]; uint4 u; } cv;
        if (gb >= 0 && gb + 7 < WW) {
            const float4 v0 = *reinterpret_cast<const float4*>(rp + gb);
            const float4 v1 = *reinterpret_cast<const float4*>(rp + gb + 4);
            cv.h2[0] = __floats2half2_rn(v0.x, v0.y);
            cv.h2[1] = __floats2half2_rn(v0.z, v0.w);
            cv.h2[2] = __floats2half2_rn(v1.x, v1.y);
            cv.h2[3] = __floats2half2_rn(v1.z, v1.w);
        } else {
#pragma unroll
            for (int e = 0; e < 4; ++e)
                cv.h2[e] = __floats2half2_rn(rp[reflect_idx(gb + 2 * e, WW)],
                                             rp[reflect_idx(gb + 2 * e + 1, WW)]);
        }
        *reinterpret_cast<uint4*>(buf + row * ROWB + c8 * 16) = cv.u;
    }
}

__device__ __forceinline__ void stage_f16(const __half* __restrict__ src, char* buf,
                                          int h0, int w0, int wv, int lane) {
#pragma unroll
    for (int c0 = 0; c0 < 4; ++c0) {               // 13 chunks over 4 waves
        int c = c0 * 4 + wv;
        if (c < 13) {
            int byt = c * 1024 + lane * 16;
            if (byt < PLANE_BYTES) {               // tail of chunk 12 masked
                int row  = byt / ROWB;
                int colh = (byt - row * ROWB) >> 1;
                int gh = reflect_idx(h0 - 8 + row, HH);
                async_cp16(src + (size_t)gh * SP + (w0 + colh), buf + byt);
            }
        }
    }
}

// PASS 1: in = f32 x (unpadded), out = f16 ypad (stride SP, reflect-padded cols)
// PASS 2: in = f16 ypad,         out = f32 z   (unpadded)
template <int PASS>
__global__ __launch_bounds__(256, 3) void conv_mfma(const void* __restrict__ xin,
                                                    void* __restrict__ outp,
                                                    const __half* __restrict__ bfrag) {
    __shared__ char lds[LDS_BYTES];

    const int bt = blockIdx.z;
    const int t  = bt % TT;
    const int h0 = blockIdx.y * BTILE;
    const int w0 = blockIdx.x * BTILE;
    const int tid = threadIdx.x;
    const int lane = tid & 63;
    const int wv = tid >> 6;

    char* buf0 = lds;
    char* buf1 = lds + PLANE_BYTES;
    char* ldsB = lds + BLDS_OFF;

    const int tprev = (t == 0) ? 1 : t - 1;
    const int tnext = (t == TT - 1) ? TT - 2 : t + 1;
    const int bbase = (bt / TT) * TT;

    // Named frame pointers (no arrays -> no scratch)
    const float *xf0 = nullptr, *xf1 = nullptr, *xf2 = nullptr;
    const __half *yf0 = nullptr, *yf1 = nullptr, *yf2 = nullptr;
    if constexpr (PASS == 1) {
        const float* x = (const float*)xin;
        const size_t fs = (size_t)HH * WW;
        xf0 = x + (size_t)(bbase + tprev) * fs;
        xf1 = x + (size_t)bt * fs;
        xf2 = x + (size_t)(bbase + tnext) * fs;
    } else {
        const __half* y = (const __half*)xin;
        const size_t fsP = (size_t)HH * SP;
        yf0 = y + (size_t)(bbase + tprev) * fsP;
        yf1 = y + (size_t)bt * fsP;
        yf2 = y + (size_t)(bbase + tnext) * fsP;
    }

    // ---- One-time cooperative DMA: all 27 B-fragments global -> LDS ----
#pragma unroll
    for (int c0 = 0; c0 < 7; ++c0) {               // 27 x 1024B chunks over 4 waves
        int c = c0 * 4 + wv;
        if (c < 27)
            async_cp16((const char*)bfrag + c * 1024 + lane * 16, ldsB + c * 1024 + lane * 16);
    }

    const float bias = *reinterpret_cast<const float*>(bfrag + 27 * 64 * 8);
    f32x4 acc0 = {bias, bias, bias, bias};
    f32x4 acc1 = acc0, acc2 = acc0, acc3 = acc0;

    const int i16 = lane & 15;
    const int kg  = lane >> 4;
    const int aoff = (16 * wv + i16) * ROWB + kg * 16;
    const char* bB = ldsB + lane * 16;             // + (ch*9+ri)*1024 literal

#define STAGE_CH(CH, BUF)                                                        \
    do {                                                                         \
        if constexpr (PASS == 1)                                                 \
            stage_f32((CH) == 0 ? xf0 : (CH) == 1 ? xf1 : xf2, BUF, h0, w0, tid);\
        else                                                                     \
            stage_f16((CH) == 0 ? yf0 : (CH) == 1 ? yf1 : yf2, BUF, h0, w0, wv, lane); \
    } while (0)

#define COMPUTE_CH(CH, BUF)                                                      \
    do {                                                                         \
        const char* aB = (BUF) + aoff;                                           \
        _Pragma("unroll")                                                        \
        for (int ri = 0; ri < 9; ++ri) {                                         \
            const half8 b = *reinterpret_cast<const half8*>(bB + ((CH) * 9 + ri) * 1024); \
            const char* ar = aB + (kR[ri] + 8) * ROWB;                           \
            half8 a0 = *reinterpret_cast<const half8*>(ar);                      \
            half8 a1 = *reinterpret_cast<const half8*>(ar + 32);                 \
            half8 a2 = *reinterpret_cast<const half8*>(ar + 64);                 \
            half8 a3 = *reinterpret_cast<const half8*>(ar + 96);                 \
            __builtin_amdgcn_s_setprio(1);                                       \
            acc0 = __builtin_amdgcn_mfma_f32_16x16x32_f16(a0, b, acc0, 0, 0, 0); \
            acc1 = __builtin_amdgcn_mfma_f32_16x16x32_f16(a1, b, acc1, 0, 0, 0); \
            acc2 = __builtin_amdgcn_mfma_f32_16x16x32_f16(a2, b, acc2, 0, 0, 0); \
            acc3 = __builtin_amdgcn_mfma_f32_16x16x32_f16(a3, b, acc3, 0, 0, 0); \
            __builtin_amdgcn_s_setprio(0);                                       \
        }                                                                        \
    } while (0)

    // ---- proven ping-pong schedule (r14), channels fully unrolled ----
    STAGE_CH(0, buf0);
    asm volatile("s_waitcnt vmcnt(0)" ::: "memory");   // B-DMA (+stage DMA in pass 2)
    __syncthreads();
    STAGE_CH(1, buf1);
    COMPUTE_CH(0, buf0);

    if constexpr (PASS == 2) asm volatile("s_waitcnt vmcnt(0)" ::: "memory");
    __syncthreads();
    STAGE_CH(2, buf0);
    COMPUTE_CH(1, buf1);

    if constexpr (PASS == 2) asm volatile("s_waitcnt vmcnt(0)" ::: "memory");
    __syncthreads();
    COMPUTE_CH(2, buf0);

#undef STAGE_CH
#undef COMPUTE_CH

    // ---- Epilogue: tanh; C layout col=lane&15, row=(lane>>4)*4+reg ----
    if constexpr (PASS == 1) {
        __half* yp = (__half*)outp + (size_t)bt * HH * SP;
#pragma unroll
        for (int sc = 0; sc < 4; ++sc) {
            f32x4 a = (sc == 0) ? acc0 : (sc == 1) ? acc1 : (sc == 2) ? acc2 : acc3;
            const int wcol = w0 + sc * 16 + i16;
#pragma unroll
            for (int v2 = 0; v2 < 4; ++v2) {
                float z = a[v2];
                float e = __expf(2.0f * z);
                z = 1.0f - 2.0f / (e + 1.0f);
                __half hz = __float2half(z);
                __half* rb = yp + (size_t)(h0 + 16 * wv + kg * 4 + v2) * SP;
                rb[8 + wcol] = hz;
                if (wcol >= 1 && wcol <= 8)          rb[8 - wcol] = hz;       // left mirror
                else if (wcol >= 503 && wcol <= 510) rb[1030 - wcol] = hz;    // right mirror
            }
        }
    } else {
        float* dst = (float*)outp + (size_t)bt * HH * WW
                   + (size_t)(h0 + 16 * wv + kg * 4) * WW + (w0 + i16);
#pragma unroll
        for (int sc = 0; sc < 4; ++sc) {
            f32x4 a = (sc == 0) ? acc0 : (sc == 1) ? acc1 : (sc == 2) ? acc2 : acc3;
#pragma unroll
            for (int v2 = 0; v2 < 4; ++v2) {
                float z = a[v2];
                float e = __expf(2.0f * z);
                dst[(size_t)v2 * WW + sc * 16] = 1.0f - 2.0f / (e + 1.0f);
            }
        }
    }
}

extern "C" void kernel_launch(void* const* d_in, const int* in_sizes, int n_in,
                              void* d_out, int out_size, void* d_ws, size_t ws_size,
                              hipStream_t stream) {
    const float* x = (const float*)d_in[0];
    char* ws = (char*)d_ws;
    __half* bf1  = (__half*)ws;                        // 27.7 KB
    __half* bf2  = (__half*)(ws + 32768);              // 27.7 KB
    __half* ypad = (__half*)(ws + 65536);              // 64 x 512 x 528 f16 = 34.6 MB

    pack_bfrag<<<1, 256, 0, stream>>>((const float*)d_in[1], (const float*)d_in[2],
                                      (const float*)d_in[3], (const float*)d_in[4],
                                      (const float*)d_in[5], (const float*)d_in[6],
                                      (const float*)d_in[7], (const float*)d_in[8],
                                      (const float*)d_in[9], bf1);
    pack_bfrag<<<1, 256, 0, stream>>>((const float*)d_in[10], (const float*)d_in[11],
                                      (const float*)d_in[12], (const float*)d_in[13],
                                      (const float*)d_in[14], (const float*)d_in[15],
                                      (const float*)d_in[16], (const float*)d_in[17],
                                      (const float*)d_in[18], bf2);

    dim3 grid(WW / BTILE, HH / BTILE, BB * TT);   // 8 x 8 x 64
    conv_mfma<1><<<grid, 256, 0, stream>>>(x, ypad, bf1);
    conv_mfma<2><<<grid, 256, 0, stream>>>(ypad, d_out, bf2);
}

// Round 18
// 157.390 us; speedup vs baseline: 2.5355x; 1.0026x over previous
//
#include <hip/hip_runtime.h>
#include <hip/hip_fp16.h>

// Problem constants
#define BB 4
#define TT 16
#define HH 512
#define WW 512
#define SP 528                        // padded row stride (halfs) of the f16 inter-pass buffer

// 256 threads = 4 waves; output 64x64. Wave wv owns rows 16wv..16wv+15 x 64 cols.
// LDS: 2 ping-pong channel planes + resident copy of all 27 B-fragments.
#define BTILE 64
#define ROWB 160                      // plane row stride bytes (80 halfs)
#define PROWS 80                      // 64 + 2*8 halo
#define PLANE_BYTES (PROWS * ROWB)    // 12800
#define BLDS_OFF (2 * PLANE_BYTES)    // 25600
#define BFRAG_BYTES 27648             // 27 mats x 64 lanes x 16 B
#define LDS_BYTES (BLDS_OFF + BFRAG_BYTES)   // 53248 -> 3 blocks/CU

typedef _Float16 half8 __attribute__((ext_vector_type(8)));
typedef float f32x4 __attribute__((ext_vector_type(4)));

constexpr int kR[9] = {-8, -4, -2, -1, 0, 1, 2, 4, 8};   // merged tap rows

__device__ __forceinline__ int reflect_idx(int q, int n) {
    q = abs(q);
    if (q >= n) q = 2 * n - 2 - q;
    return q;
}

__device__ __forceinline__ void async_cp16(const void* g, char* l) {
#if __has_builtin(__builtin_amdgcn_global_load_lds)
    __builtin_amdgcn_global_load_lds(
        (const __attribute__((address_space(1))) unsigned int*)g,
        (__attribute__((address_space(3))) unsigned int*)l, 16, 0, 0);
#else
    *reinterpret_cast<uint4*>(l) = *reinterpret_cast<const uint4*>(g);
#endif
}

// 27 B-fragment matrices (ch x tap-row), 32x16 f16 banded-Toeplitz in MFMA fragment order:
// frag[(ch*9+ri)*64 + lane][e], B[k][j], j=lane&15, k=8*(lane>>4)+e, val=merged_w[ch][r][k-8-j].
// Combined bias stored as float at halfs[27*64*8].
__global__ void pack_bfrag(const float* __restrict__ w1, const float* __restrict__ b1,
                           const float* __restrict__ w2, const float* __restrict__ b2,
                           const float* __restrict__ w3, const float* __restrict__ b3,
                           const float* __restrict__ sa, const float* __restrict__ sb,
                           const float* __restrict__ sc_, __half* __restrict__ bfrag) {
    const int tid = threadIdx.x;
    float s[3] = {sa[0], sb[0], sc_[0]};
    const float* wp[3] = {w1, w2, w3};
    for (int idx = tid; idx < 27 * 64; idx += blockDim.x) {
        int mat = idx >> 6;
        int lane = idx & 63;
        int ch = mat / 9, ri = mat % 9;
        int r = kR[ri];
        int j = lane & 15, kg = lane >> 4;
        union { __half h[8]; uint4 u; } v;
#pragma unroll
        for (int e = 0; e < 8; ++e) {
            int k = kg * 8 + e;
            int c = k - 8 - j;
            float a = 0.f;
            if (c >= -8 && c <= 8) {
                for (int b = 0; b < 3; ++b) {
                    int d = 1 << b;
                    if (r % d == 0 && c % d == 0) {
                        int rd = r / d, cd = c / d;
                        if (rd >= -2 && rd <= 2 && cd >= -2 && cd <= 2)
                            a += s[b] * wp[b][ch * 25 + (rd + 2) * 5 + (cd + 2)];
                    }
                }
            }
            v.h[e] = __float2half(a);
        }
        *reinterpret_cast<uint4*>(bfrag + idx * 8) = v.u;
    }
    if (tid == 0)
        *reinterpret_cast<float*>(bfrag + 27 * 64 * 8) = s[0] * b1[0] + s[1] * b2[0] + s[2] * b3[0];
}

// ---- STAGE helpers: static control flow, named src pointers ----
__device__ __forceinline__ void stage_f32(const float* __restrict__ src, char* buf,
                                          int h0, int w0, int tid) {
    for (int k2 = tid; k2 < PROWS * 10; k2 += 256) {
        int row = k2 / 10;
        int c8  = k2 - row * 10;
        int gh = reflect_idx(h0 - 8 + row, HH);
        int gb = w0 - 8 + c8 * 8;
        const float* rp = src + (size_t)gh * WW;
        union { __half2 h2[4]; uint4 u; } cv;
        if (gb >= 0 && gb + 7 < WW) {
            const float4 v0 = *reinterpret_cast<const float4*>(rp + gb);
            const float4 v1 = *reinterpret_cast<const float4*>(rp + gb + 4);
            cv.h2[0] = __floats2half2_rn(v0.x, v0.y);
            cv.h2[1] = __floats2half2_rn(v0.z, v0.w);
            cv.h2[2] = __floats2half2_rn(v1.x, v1.y);
            cv.h2[3] = __floats2half2_rn(v1.z, v1.w);
        } else {
#pragma unroll
            for (int e = 0; e < 4; ++e)
                cv.h2[e] = __floats2half2_rn(rp[reflect_idx(gb + 2 * e, WW)],
                                             rp[reflect_idx(gb + 2 * e + 1, WW)]);
        }
        *reinterpret_cast<uint4*>(buf + row * ROWB + c8 * 16) = cv.u;
    }
}

__device__ __forceinline__ void stage_f16(const __half* __restrict__ src, char* buf,
                                          int h0, int w0, int wv, int lane) {
#pragma unroll
    for (int c0 = 0; c0 < 4; ++c0) {               // 13 chunks over 4 waves
        int c = c0 * 4 + wv;
        if (c < 13) {
            int byt = c * 1024 + lane * 16;
            if (byt < PLANE_BYTES) {               // tail of chunk 12 masked
                int row  = byt / ROWB;
                int colh = (byt - row * ROWB) >> 1;
                int gh = reflect_idx(h0 - 8 + row, HH);
                async_cp16(src + (size_t)gh * SP + (w0 + colh), buf + byt);
            }
        }
    }
}

// PASS 1: in = f32 x (unpadded), out = f16 ypad (stride SP, reflect-padded cols)
// PASS 2: in = f16 ypad,         out = f32 z   (unpadded)
template <int PASS>
__global__ __launch_bounds__(256, 3) void conv_mfma(const void* __restrict__ xin,
                                                    void* __restrict__ outp,
                                                    const __half* __restrict__ bfrag) {
    __shared__ char lds[LDS_BYTES];

    const int bt = blockIdx.z;
    const int t  = bt % TT;
    const int h0 = blockIdx.y * BTILE;
    const int w0 = blockIdx.x * BTILE;
    const int tid = threadIdx.x;
    const int lane = tid & 63;
    const int wv = tid >> 6;

    char* buf0 = lds;
    char* buf1 = lds + PLANE_BYTES;
    char* ldsB = lds + BLDS_OFF;

    const int tprev = (t == 0) ? 1 : t - 1;
    const int tnext = (t == TT - 1) ? TT - 2 : t + 1;
    const int bbase = (bt / TT) * TT;

    // Named frame pointers (no arrays -> no scratch)
    const float *xf0 = nullptr, *xf1 = nullptr, *xf2 = nullptr;
    const __half *yf0 = nullptr, *yf1 = nullptr, *yf2 = nullptr;
    if constexpr (PASS == 1) {
        const float* x = (const float*)xin;
        const size_t fs = (size_t)HH * WW;
        xf0 = x + (size_t)(bbase + tprev) * fs;
        xf1 = x + (size_t)bt * fs;
        xf2 = x + (size_t)(bbase + tnext) * fs;
    } else {
        const __half* y = (const __half*)xin;
        const size_t fsP = (size_t)HH * SP;
        yf0 = y + (size_t)(bbase + tprev) * fsP;
        yf1 = y + (size_t)bt * fsP;
        yf2 = y + (size_t)(bbase + tnext) * fsP;
    }

    // ---- One-time cooperative DMA: all 27 B-fragments global -> LDS ----
#pragma unroll
    for (int c0 = 0; c0 < 7; ++c0) {               // 27 x 1024B chunks over 4 waves
        int c = c0 * 4 + wv;
        if (c < 27)
            async_cp16((const char*)bfrag + c * 1024 + lane * 16, ldsB + c * 1024 + lane * 16);
    }

    const float bias = *reinterpret_cast<const float*>(bfrag + 27 * 64 * 8);
    f32x4 acc0 = {bias, bias, bias, bias};
    f32x4 acc1 = acc0, acc2 = acc0, acc3 = acc0;

    const int i16 = lane & 15;
    const int kg  = lane >> 4;
    const int aoff = (16 * wv + i16) * ROWB + kg * 16;
    const char* bB = ldsB + lane * 16;             // + (ch*9+ri)*1024 literal

#define STAGE_CH(CH, BUF)                                                        \
    do {                                                                         \
        if constexpr (PASS == 1)                                                 \
            stage_f32((CH) == 0 ? xf0 : (CH) == 1 ? xf1 : xf2, BUF, h0, w0, tid);\
        else                                                                     \
            stage_f16((CH) == 0 ? yf0 : (CH) == 1 ? yf1 : yf2, BUF, h0, w0, wv, lane); \
    } while (0)

#define COMPUTE_CH(CH, BUF)                                                      \
    do {                                                                         \
        const char* aB = (BUF) + aoff;                                           \
        _Pragma("unroll")                                                        \
        for (int ri = 0; ri < 9; ++ri) {                                         \
            const half8 b = *reinterpret_cast<const half8*>(bB + ((CH) * 9 + ri) * 1024); \
            const char* ar = aB + (kR[ri] + 8) * ROWB;                           \
            half8 a0 = *reinterpret_cast<const half8*>(ar);                      \
            half8 a1 = *reinterpret_cast<const half8*>(ar + 32);                 \
            half8 a2 = *reinterpret_cast<const half8*>(ar + 64);                 \
            half8 a3 = *reinterpret_cast<const half8*>(ar + 96);                 \
            __builtin_amdgcn_s_setprio(1);                                       \
            acc0 = __builtin_amdgcn_mfma_f32_16x16x32_f16(a0, b, acc0, 0, 0, 0); \
            acc1 = __builtin_amdgcn_mfma_f32_16x16x32_f16(a1, b, acc1, 0, 0, 0); \
            acc2 = __builtin_amdgcn_mfma_f32_16x16x32_f16(a2, b, acc2, 0, 0, 0); \
            acc3 = __builtin_amdgcn_mfma_f32_16x16x32_f16(a3, b, acc3, 0, 0, 0); \
            __builtin_amdgcn_s_setprio(0);                                       \
        }                                                                        \
    } while (0)

    // ---- proven ping-pong schedule (r14), channels fully unrolled ----
    STAGE_CH(0, buf0);
    asm volatile("s_waitcnt vmcnt(0)" ::: "memory");   // B-DMA (+stage DMA in pass 2)
    __syncthreads();
    STAGE_CH(1, buf1);
    COMPUTE_CH(0, buf0);

    if constexpr (PASS == 2) asm volatile("s_waitcnt vmcnt(0)" ::: "memory");
    __syncthreads();
    STAGE_CH(2, buf0);
    COMPUTE_CH(1, buf1);

    if constexpr (PASS == 2) asm volatile("s_waitcnt vmcnt(0)" ::: "memory");
    __syncthreads();
    COMPUTE_CH(2, buf0);

#undef STAGE_CH
#undef COMPUTE_CH

    // ---- Epilogue: tanh; C layout col=lane&15, row=(lane>>4)*4+reg ----
    if constexpr (PASS == 1) {
        __half* yp = (__half*)outp + (size_t)bt * HH * SP;
#pragma unroll
        for (int sc = 0; sc < 4; ++sc) {
            f32x4 a = (sc == 0) ? acc0 : (sc == 1) ? acc1 : (sc == 2) ? acc2 : acc3;
            const int wcol = w0 + sc * 16 + i16;
#pragma unroll
            for (int v2 = 0; v2 < 4; ++v2) {
                float z = a[v2];
                float e = __expf(2.0f * z);
                z = 1.0f - 2.0f / (e + 1.0f);
                __half hz = __float2half(z);
                __half* rb = yp + (size_t)(h0 + 16 * wv + kg * 4 + v2) * SP;
                rb[8 + wcol] = hz;
                if (wcol >= 1 && wcol <= 8)          rb[8 - wcol] = hz;       // left mirror
                else if (wcol >= 503 && wcol <= 510) rb[1030 - wcol] = hz;    // right mirror
            }
        }
    } else {
        float* dst = (float*)outp + (size_t)bt * HH * WW
                   + (size_t)(h0 + 16 * wv + kg * 4) * WW + (w0 + i16);
#pragma unroll
        for (int sc = 0; sc < 4; ++sc) {
            f32x4 a = (sc == 0) ? acc0 : (sc == 1) ? acc1 : (sc == 2) ? acc2 : acc3;
#pragma unroll
            for (int v2 = 0; v2 < 4; ++v2) {
                float z = a[v2];
                float e = __expf(2.0f * z);
                dst[(size_t)v2 * WW + sc * 16] = 1.0f - 2.0f / (e + 1.0f);
            }
        }
    }
}

extern "C" void kernel_launch(void* const* d_in, const int* in_sizes, int n_in,
                              void* d_out, int out_size, void* d_ws, size_t ws_size,
                              hipStream_t stream) {
    const float* x = (const float*)d_in[0];
    char* ws = (char*)d_ws;
    __half* bf1  = (__half*)ws;                        // 27.7 KB
    __half* bf2  = (__half*)(ws + 32768);              // 27.7 KB
    __half* ypad = (__half*)(ws + 65536);              // 64 x 512 x 528 f16 = 34.6 MB

    pack_bfrag<<<1, 256, 0, stream>>>((const float*)d_in[1], (const float*)d_in[2],
                                      (const float*)d_in[3], (const float*)d_in[4],
                                      (const float*)d_in[5], (const float*)d_in[6],
                                      (const float*)d_in[7], (const float*)d_in[8],
                                      (const float*)d_in[9], bf1);
    pack_bfrag<<<1, 256, 0, stream>>>((const float*)d_in[10], (const float*)d_in[11],
                                      (const float*)d_in[12], (const float*)d_in[13],
                                      (const float*)d_in[14], (const float*)d_in[15],
                                      (const float*)d_in[16], (const float*)d_in[17],
                                      (const float*)d_in[18], bf2);

    dim3 grid(WW / BTILE, HH / BTILE, BB * TT);   // 8 x 8 x 64
    conv_mfma<1><<<grid, 256, 0, stream>>>(x, ypad, bf1);
    conv_mfma<2><<<grid, 256, 0, stream>>>(ypad, d_out, bf2);
}

// Round 19
// 140.200 us; speedup vs baseline: 2.8463x; 1.1226x over previous
//
#include <hip/hip_runtime.h>
#include <hip/hip_fp16.h>

// Problem constants
#define BB 4
#define TT 16
#define HH 512
#define WW 512
#define SP 528                        // padded row stride (halfs) of the f16 inter-pass buffer

// 512 threads = 8 waves; output 64x64. Wave (rs,chf): rows 16rs..16rs+15,
// cols 32chf..32chf+31 (2 MFMA col strips -> 2 acc chains).
// LDS: 2 ping-pong channel planes + resident copy of all 27 B-fragments.
#define BTILE 64
#define ROWB 160                      // plane row stride bytes (80 halfs)
#define PROWS 80                      // 64 + 2*8 halo
#define PLANE_BYTES (PROWS * ROWB)    // 12800
#define BLDS_OFF (2 * PLANE_BYTES)    // 25600
#define BFRAG_BYTES 27648             // 27 mats x 64 lanes x 16 B
#define LDS_BYTES (BLDS_OFF + BFRAG_BYTES)   // 53248 -> 3 blocks/CU, 24 waves/CU

typedef _Float16 half8 __attribute__((ext_vector_type(8)));
typedef float f32x4 __attribute__((ext_vector_type(4)));

constexpr int kR[9] = {-8, -4, -2, -1, 0, 1, 2, 4, 8};   // merged tap rows

__device__ __forceinline__ int reflect_idx(int q, int n) {
    q = abs(q);
    if (q >= n) q = 2 * n - 2 - q;
    return q;
}

__device__ __forceinline__ void async_cp16(const void* g, char* l) {
#if __has_builtin(__builtin_amdgcn_global_load_lds)
    __builtin_amdgcn_global_load_lds(
        (const __attribute__((address_space(1))) unsigned int*)g,
        (__attribute__((address_space(3))) unsigned int*)l, 16, 0, 0);
#else
    *reinterpret_cast<uint4*>(l) = *reinterpret_cast<const uint4*>(g);
#endif
}

// 27 B-fragment matrices (ch x tap-row), 32x16 f16 banded-Toeplitz in MFMA fragment order:
// frag[(ch*9+ri)*64 + lane][e], B[k][j], j=lane&15, k=8*(lane>>4)+e, val=merged_w[ch][r][k-8-j].
// Combined bias stored as float at halfs[27*64*8].
__global__ void pack_bfrag(const float* __restrict__ w1, const float* __restrict__ b1,
                           const float* __restrict__ w2, const float* __restrict__ b2,
                           const float* __restrict__ w3, const float* __restrict__ b3,
                           const float* __restrict__ sa, const float* __restrict__ sb,
                           const float* __restrict__ sc_, __half* __restrict__ bfrag) {
    const int tid = threadIdx.x;
    float s[3] = {sa[0], sb[0], sc_[0]};
    const float* wp[3] = {w1, w2, w3};
    for (int idx = tid; idx < 27 * 64; idx += blockDim.x) {
        int mat = idx >> 6;
        int lane = idx & 63;
        int ch = mat / 9, ri = mat % 9;
        int r = kR[ri];
        int j = lane & 15, kg = lane >> 4;
        union { __half h[8]; uint4 u; } v;
#pragma unroll
        for (int e = 0; e < 8; ++e) {
            int k = kg * 8 + e;
            int c = k - 8 - j;
            float a = 0.f;
            if (c >= -8 && c <= 8) {
                for (int b = 0; b < 3; ++b) {
                    int d = 1 << b;
                    if (r % d == 0 && c % d == 0) {
                        int rd = r / d, cd = c / d;
                        if (rd >= -2 && rd <= 2 && cd >= -2 && cd <= 2)
                            a += s[b] * wp[b][ch * 25 + (rd + 2) * 5 + (cd + 2)];
                    }
                }
            }
            v.h[e] = __float2half(a);
        }
        *reinterpret_cast<uint4*>(bfrag + idx * 8) = v.u;
    }
    if (tid == 0)
        *reinterpret_cast<float*>(bfrag + 27 * 64 * 8) = s[0] * b1[0] + s[1] * b2[0] + s[2] * b3[0];
}

// ---- STAGE helpers: static control flow, named src pointers ----
__device__ __forceinline__ void stage_f32(const float* __restrict__ src, char* buf,
                                          int h0, int w0, int tid) {
    for (int k2 = tid; k2 < PROWS * 10; k2 += 512) {
        int row = k2 / 10;
        int c8  = k2 - row * 10;
        int gh = reflect_idx(h0 - 8 + row, HH);
        int gb = w0 - 8 + c8 * 8;
        const float* rp = src + (size_t)gh * WW;
        union { __half2 h2[4]; uint4 u; } cv;
        if (gb >= 0 && gb + 7 < WW) {
            const float4 v0 = *reinterpret_cast<const float4*>(rp + gb);
            const float4 v1 = *reinterpret_cast<const float4*>(rp + gb + 4);
            cv.h2[0] = __floats2half2_rn(v0.x, v0.y);
            cv.h2[1] = __floats2half2_rn(v0.z, v0.w);
            cv.h2[2] = __floats2half2_rn(v1.x, v1.y);
            cv.h2[3] = __floats2half2_rn(v1.z, v1.w);
        } else {
#pragma unroll
            for (int e = 0; e < 4; ++e)
                cv.h2[e] = __floats2half2_rn(rp[reflect_idx(gb + 2 * e, WW)],
                                             rp[reflect_idx(gb + 2 * e + 1, WW)]);
        }
        *reinterpret_cast<uint4*>(buf + row * ROWB + c8 * 16) = cv.u;
    }
}

__device__ __forceinline__ void stage_f16(const __half* __restrict__ src, char* buf,
                                          int h0, int w0, int wv, int lane) {
#pragma unroll
    for (int c0 = 0; c0 < 2; ++c0) {               // 13 chunks over 8 waves
        int c = c0 * 8 + wv;
        if (c < 13) {
            int byt = c * 1024 + lane * 16;
            if (byt < PLANE_BYTES) {               // tail of chunk 12 masked
                int row  = byt / ROWB;
                int colh = (byt - row * ROWB) >> 1;
                int gh = reflect_idx(h0 - 8 + row, HH);
                async_cp16(src + (size_t)gh * SP + (w0 + colh), buf + byt);
            }
        }
    }
}

// PASS 1: in = f32 x (unpadded), out = f16 ypad (stride SP, reflect-padded cols)
// PASS 2: in = f16 ypad,         out = f32 z   (unpadded)
template <int PASS>
__global__ __launch_bounds__(512, 6) void conv_mfma(const void* __restrict__ xin,
                                                    void* __restrict__ outp,
                                                    const __half* __restrict__ bfrag) {
    __shared__ char lds[LDS_BYTES];

    const int bt = blockIdx.z;
    const int t  = bt % TT;
    const int h0 = blockIdx.y * BTILE;
    const int w0 = blockIdx.x * BTILE;
    const int tid = threadIdx.x;
    const int lane = tid & 63;
    const int wv = tid >> 6;                  // 0..7
    const int rs  = wv >> 1;                  // row strip 0..3
    const int chf = wv & 1;                   // col half 0..1

    char* buf0 = lds;
    char* buf1 = lds + PLANE_BYTES;
    char* ldsB = lds + BLDS_OFF;

    const int tprev = (t == 0) ? 1 : t - 1;
    const int tnext = (t == TT - 1) ? TT - 2 : t + 1;
    const int bbase = (bt / TT) * TT;

    // Named frame pointers (no arrays -> no scratch)
    const float *xf0 = nullptr, *xf1 = nullptr, *xf2 = nullptr;
    const __half *yf0 = nullptr, *yf1 = nullptr, *yf2 = nullptr;
    if constexpr (PASS == 1) {
        const float* x = (const float*)xin;
        const size_t fs = (size_t)HH * WW;
        xf0 = x + (size_t)(bbase + tprev) * fs;
        xf1 = x + (size_t)bt * fs;
        xf2 = x + (size_t)(bbase + tnext) * fs;
    } else {
        const __half* y = (const __half*)xin;
        const size_t fsP = (size_t)HH * SP;
        yf0 = y + (size_t)(bbase + tprev) * fsP;
        yf1 = y + (size_t)bt * fsP;
        yf2 = y + (size_t)(bbase + tnext) * fsP;
    }

    // ---- One-time cooperative DMA: all 27 B-fragments global -> LDS ----
#pragma unroll
    for (int c0 = 0; c0 < 4; ++c0) {               // 27 x 1024B chunks over 8 waves
        int c = c0 * 8 + wv;
        if (c < 27)
            async_cp16((const char*)bfrag + c * 1024 + lane * 16, ldsB + c * 1024 + lane * 16);
    }

    const float bias = *reinterpret_cast<const float*>(bfrag + 27 * 64 * 8);
    f32x4 acc0 = {bias, bias, bias, bias};
    f32x4 acc1 = acc0;

    const int i16 = lane & 15;
    const int kg  = lane >> 4;
    const int aoff = (16 * rs + i16) * ROWB + kg * 16 + chf * 64;
    const char* bB = ldsB + lane * 16;             // + (ch*9+ri)*1024 literal

#define STAGE_CH(CH, BUF)                                                        \
    do {                                                                         \
        if constexpr (PASS == 1)                                                 \
            stage_f32((CH) == 0 ? xf0 : (CH) == 1 ? xf1 : xf2, BUF, h0, w0, tid);\
        else                                                                     \
            stage_f16((CH) == 0 ? yf0 : (CH) == 1 ? yf1 : yf2, BUF, h0, w0, wv, lane); \
    } while (0)

#define COMPUTE_CH(CH, BUF)                                                      \
    do {                                                                         \
        const char* aB = (BUF) + aoff;                                           \
        _Pragma("unroll")                                                        \
        for (int ri = 0; ri < 9; ++ri) {                                         \
            const half8 b = *reinterpret_cast<const half8*>(bB + ((CH) * 9 + ri) * 1024); \
            const char* ar = aB + (kR[ri] + 8) * ROWB;                           \
            half8 a0 = *reinterpret_cast<const half8*>(ar);                      \
            half8 a1 = *reinterpret_cast<const half8*>(ar + 32);                 \
            __builtin_amdgcn_s_setprio(1);                                       \
            acc0 = __builtin_amdgcn_mfma_f32_16x16x32_f16(a0, b, acc0, 0, 0, 0); \
            acc1 = __builtin_amdgcn_mfma_f32_16x16x32_f16(a1, b, acc1, 0, 0, 0); \
            __builtin_amdgcn_s_setprio(0);                                       \
        }                                                                        \
    } while (0)

    // ---- proven ping-pong schedule (r14/r18), channels fully unrolled ----
    STAGE_CH(0, buf0);
    asm volatile("s_waitcnt vmcnt(0)" ::: "memory");   // B-DMA (+stage DMA in pass 2)
    __syncthreads();
    STAGE_CH(1, buf1);
    COMPUTE_CH(0, buf0);

    if constexpr (PASS == 2) asm volatile("s_waitcnt vmcnt(0)" ::: "memory");
    __syncthreads();
    STAGE_CH(2, buf0);
    COMPUTE_CH(1, buf1);

    if constexpr (PASS == 2) asm volatile("s_waitcnt vmcnt(0)" ::: "memory");
    __syncthreads();
    COMPUTE_CH(2, buf0);

#undef STAGE_CH
#undef COMPUTE_CH

    // ---- Epilogue: tanh; C layout col=lane&15, row=(lane>>4)*4+reg ----
    if constexpr (PASS == 1) {
        __half* yp = (__half*)outp + (size_t)bt * HH * SP;
#pragma unroll
        for (int sc = 0; sc < 2; ++sc) {
            f32x4 a = (sc == 0) ? acc0 : acc1;
            const int wcol = w0 + chf * 32 + sc * 16 + i16;
#pragma unroll
            for (int v2 = 0; v2 < 4; ++v2) {
                float z = a[v2];
                float e = __expf(2.0f * z);
                z = 1.0f - 2.0f / (e + 1.0f);
                __half hz = __float2half(z);
                __half* rb = yp + (size_t)(h0 + 16 * rs + kg * 4 + v2) * SP;
                rb[8 + wcol] = hz;
                if (wcol >= 1 && wcol <= 8)          rb[8 - wcol] = hz;       // left mirror
                else if (wcol >= 503 && wcol <= 510) rb[1030 - wcol] = hz;    // right mirror
            }
        }
    } else {
        float* dst = (float*)outp + (size_t)bt * HH * WW
                   + (size_t)(h0 + 16 * rs + kg * 4) * WW + (w0 + chf * 32 + i16);
#pragma unroll
        for (int sc = 0; sc < 2; ++sc) {
            f32x4 a = (sc == 0) ? acc0 : acc1;
#pragma unroll
            for (int v2 = 0; v2 < 4; ++v2) {
                float z = a[v2];
                float e = __expf(2.0f * z);
                dst[(size_t)v2 * WW + sc * 16] = 1.0f - 2.0f / (e + 1.0f);
            }
        }
    }
}

extern "C" void kernel_launch(void* const* d_in, const int* in_sizes, int n_in,
                              void* d_out, int out_size, void* d_ws, size_t ws_size,
                              hipStream_t stream) {
    const float* x = (const float*)d_in[0];
    char* ws = (char*)d_ws;
    __half* bf1  = (__half*)ws;                        // 27.7 KB
    __half* bf2  = (__half*)(ws + 32768);              // 27.7 KB
    __half* ypad = (__half*)(ws + 65536);              // 64 x 512 x 528 f16 = 34.6 MB

    pack_bfrag<<<1, 256, 0, stream>>>((const float*)d_in[1], (const float*)d_in[2],
                                      (const float*)d_in[3], (const float*)d_in[4],
                                      (const float*)d_in[5], (const float*)d_in[6],
                                      (const float*)d_in[7], (const float*)d_in[8],
                                      (const float*)d_in[9], bf1);
    pack_bfrag<<<1, 256, 0, stream>>>((const float*)d_in[10], (const float*)d_in[11],
                                      (const float*)d_in[12], (const float*)d_in[13],
                                      (const float*)d_in[14], (const float*)d_in[15],
                                      (const float*)d_in[16], (const float*)d_in[17],
                                      (const float*)d_in[18], bf2);

    dim3 grid(WW / BTILE, HH / BTILE, BB * TT);   // 8 x 8 x 64
    conv_mfma<1><<<grid, 512, 0, stream>>>(x, ypad, bf1);
    conv_mfma<2><<<grid, 512, 0, stream>>>(ypad, d_out, bf2);
}